// Round 2
// baseline (11336.253 us; speedup 1.0000x reference)
//
#include <hip/hip_runtime.h>
#include <math.h>

#define NN 50000
#define NE 500000
#define HID 128
#define EDIM 32

__device__ __forceinline__ float wsum(float v) {
#pragma unroll
  for (int m = 1; m < 64; m <<= 1) v += __shfl_xor(v, m, 64);
  return v;
}

// ---------------- Kernel 0: transpose GRU weights to [k][3H] ----------------
__global__ __launch_bounds__(256) void transpose_w(
    const float* __restrict__ Wih, const float* __restrict__ Whh,
    float* __restrict__ WihT, float* __restrict__ WhhT) {
  int idx = blockIdx.x * 256 + threadIdx.x;
  if (idx < 3 * HID * HID) {
    int j = idx / HID, k = idx - j * HID;  // source: row j (3H), col k (H)
    WihT[k * (3 * HID) + j] = Wih[idx];
    WhhT[k * (3 * HID) + j] = Whh[idx];
  }
}

// ---------------- Kernel 1: edge encoder + scatter-add ----------------
// 512 threads = 8 waves. W1/W2 staged in LDS once per block. Each wave
// processes 8 edges; activations broadcast from LDS via float4.
__global__ __launch_bounds__(512) void enc_kernel(
    const float* __restrict__ ea, const int* __restrict__ ei,
    const float* __restrict__ W1, const float* __restrict__ b1,
    const float* __restrict__ g1, const float* __restrict__ be1,
    const float* __restrict__ W2, const float* __restrict__ b2,
    const float* __restrict__ g2, const float* __restrict__ be2,
    float* __restrict__ aggr, float* __restrict__ cnt) {
  __shared__ __align__(16) float W1s[EDIM * HID];   // 16 KB
  __shared__ __align__(16) float W2s[HID * HID];    // 64 KB
  __shared__ __align__(16) float ea_lds[8][8][EDIM];  // 8 KB
  __shared__ __align__(16) float h1_lds[8][8][HID];   // 32 KB
  for (int i = threadIdx.x; i < EDIM * HID; i += 512) W1s[i] = W1[i];
  for (int i = threadIdx.x; i < HID * HID; i += 512) W2s[i] = W2[i];
  __syncthreads();

  const int lane = threadIdx.x & 63;
  const int w = threadIdx.x >> 6;
  const int j0 = lane, j1 = lane + 64;
  const float b1_0 = b1[j0], b1_1 = b1[j1];
  const float g1_0 = g1[j0], g1_1 = g1[j1];
  const float be1_0 = be1[j0], be1_1 = be1[j1];
  const float b2_0 = b2[j0], b2_1 = b2[j1];
  const float g2_0 = g2[j0], g2_1 = g2[j1];
  const float be2_0 = be2[j0], be2_1 = be2[j1];

  const int gwave = blockIdx.x * 8 + w;
  const int nwave = gridDim.x * 8;
  for (int base = gwave * 8; base < NE; base += nwave * 8) {
#pragma unroll
    for (int t = 0; t < 4; ++t) {
      int idx = t * 64 + lane;
      int m = idx >> 5, k = idx & 31;
      ea_lds[w][m][k] = ea[(base + m) * EDIM + k];
    }
    __asm__ volatile("s_waitcnt lgkmcnt(0)" ::: "memory");

    float a0[8], a1[8];
#pragma unroll
    for (int m = 0; m < 8; ++m) { a0[m] = b1_0; a1[m] = b1_1; }
#pragma unroll
    for (int k4 = 0; k4 < EDIM / 4; ++k4) {
      float4 ev[8];
#pragma unroll
      for (int m = 0; m < 8; ++m)
        ev[m] = *reinterpret_cast<const float4*>(&ea_lds[w][m][k4 * 4]);
#pragma unroll
      for (int kk = 0; kk < 4; ++kk) {
        int k = k4 * 4 + kk;
        float w0 = W1s[k * HID + j0];
        float w1 = W1s[k * HID + j1];
#pragma unroll
        for (int m = 0; m < 8; ++m) {
          float e = kk == 0 ? ev[m].x : kk == 1 ? ev[m].y : kk == 2 ? ev[m].z : ev[m].w;
          a0[m] = fmaf(e, w0, a0[m]);
          a1[m] = fmaf(e, w1, a1[m]);
        }
      }
    }
    // LN1 + relu -> LDS
#pragma unroll
    for (int m = 0; m < 8; ++m) {
      float s = wsum(a0[m] + a1[m]);
      float mu = s * (1.0f / HID);
      float d0 = a0[m] - mu, d1 = a1[m] - mu;
      float q = wsum(d0 * d0 + d1 * d1);
      float inv = rsqrtf(q * (1.0f / HID) + 1e-5f);
      h1_lds[w][m][j0] = fmaxf(d0 * inv * g1_0 + be1_0, 0.0f);
      h1_lds[w][m][j1] = fmaxf(d1 * inv * g1_1 + be1_1, 0.0f);
    }
    __asm__ volatile("s_waitcnt lgkmcnt(0)" ::: "memory");

    // layer 2
#pragma unroll
    for (int m = 0; m < 8; ++m) { a0[m] = b2_0; a1[m] = b2_1; }
    for (int k4 = 0; k4 < HID / 4; ++k4) {
      float4 hv[8];
#pragma unroll
      for (int m = 0; m < 8; ++m)
        hv[m] = *reinterpret_cast<const float4*>(&h1_lds[w][m][k4 * 4]);
#pragma unroll
      for (int kk = 0; kk < 4; ++kk) {
        int k = k4 * 4 + kk;
        float w0 = W2s[k * HID + j0];
        float w1 = W2s[k * HID + j1];
#pragma unroll
        for (int m = 0; m < 8; ++m) {
          float h = kk == 0 ? hv[m].x : kk == 1 ? hv[m].y : kk == 2 ? hv[m].z : hv[m].w;
          a0[m] = fmaf(h, w0, a0[m]);
          a1[m] = fmaf(h, w1, a1[m]);
        }
      }
    }
    // LN2 + relu + scatter
#pragma unroll
    for (int m = 0; m < 8; ++m) {
      float s = wsum(a0[m] + a1[m]);
      float mu = s * (1.0f / HID);
      float d0 = a0[m] - mu, d1 = a1[m] - mu;
      float q = wsum(d0 * d0 + d1 * d1);
      float inv = rsqrtf(q * (1.0f / HID) + 1e-5f);
      float e0 = fmaxf(d0 * inv * g2_0 + be2_0, 0.0f);
      float e1 = fmaxf(d1 * inv * g2_1 + be2_1, 0.0f);
      int srcn = ei[base + m];
      atomicAdd(&aggr[srcn * HID + j0], e0);
      atomicAdd(&aggr[srcn * HID + j1], e1);
      if (lane == 0) atomicAdd(&cnt[srcn], 1.0f);
    }
  }
}

// ---------------- Kernel 2: GRU + u/v precompute (fused gates) ----------------
__global__ __launch_bounds__(256) void gru_kernel(
    const float* __restrict__ aggr, const float* __restrict__ cnt,
    const float* __restrict__ h_prev,
    const float* __restrict__ WihT, const float* __restrict__ bih,
    const float* __restrict__ WhhT, const float* __restrict__ bhh,
    const float* __restrict__ Wc1,
    float* __restrict__ u, float* __restrict__ vv) {
  __shared__ __align__(16) float a_lds[4][8][HID];
  __shared__ __align__(16) float h_lds[4][8][HID];
  __shared__ __align__(16) float hn_lds[4][8][HID];
  const int lane = threadIdx.x & 63;
  const int w = threadIdx.x >> 6;
  // per-j2 bias constants
  const float br_0 = bih[lane] + bhh[lane];
  const float br_1 = bih[64 + lane] + bhh[64 + lane];
  const float bz_0 = bih[128 + lane] + bhh[128 + lane];
  const float bz_1 = bih[192 + lane] + bhh[192 + lane];
  const float bni_0 = bih[256 + lane], bni_1 = bih[320 + lane];
  const float bnh_0 = bhh[256 + lane], bnh_1 = bhh[320 + lane];

  const int gwave = blockIdx.x * 4 + w;
  const int nwave = gridDim.x * 4;
  const int ntask = NN / 8;  // 6250
  for (int task = gwave; task < ntask; task += nwave) {
    int n0 = task * 8;
#pragma unroll
    for (int t = 0; t < 16; ++t) {
      int idx = t * 64 + lane;
      int m = idx >> 7, k = idx & 127;
      int node = n0 + m;
      float ic = 1.0f / fmaxf(cnt[node], 1.0f);
      a_lds[w][m][k] = aggr[node * HID + k] * ic;
      h_lds[w][m][k] = h_prev[node * HID + k];
    }
    __asm__ volatile("s_waitcnt lgkmcnt(0)" ::: "memory");

#pragma unroll
    for (int j2 = 0; j2 < 2; ++j2) {
      const int j = lane + 64 * j2;
      float accr[8], accz[8], axn[8], ahn[8];
      const float br = j2 == 0 ? br_0 : br_1;
      const float bz = j2 == 0 ? bz_0 : bz_1;
      const float bni = j2 == 0 ? bni_0 : bni_1;
      const float bnh = j2 == 0 ? bnh_0 : bnh_1;
#pragma unroll
      for (int m = 0; m < 8; ++m) {
        accr[m] = br; accz[m] = bz; axn[m] = bni; ahn[m] = bnh;
      }
      const float* wiT = WihT + j;
      const float* whT = WhhT + j;
#pragma unroll 2
      for (int k = 0; k < HID; ++k) {
        float wir = wiT[k * 384];
        float wiz = wiT[k * 384 + 128];
        float win = wiT[k * 384 + 256];
        float whr = whT[k * 384];
        float whz = whT[k * 384 + 128];
        float whn = whT[k * 384 + 256];
#pragma unroll
        for (int m = 0; m < 8; ++m) {
          float a = a_lds[w][m][k], h = h_lds[w][m][k];
          accr[m] = fmaf(a, wir, accr[m]);
          accr[m] = fmaf(h, whr, accr[m]);
          accz[m] = fmaf(a, wiz, accz[m]);
          accz[m] = fmaf(h, whz, accz[m]);
          axn[m] = fmaf(a, win, axn[m]);
          ahn[m] = fmaf(h, whn, ahn[m]);
        }
      }
#pragma unroll
      for (int m = 0; m < 8; ++m) {
        float r = 1.0f / (1.0f + expf(-accr[m]));
        float z = 1.0f / (1.0f + expf(-accz[m]));
        float nval = tanhf(axn[m] + r * ahn[m]);
        float hp = h_lds[w][m][j];
        hn_lds[w][m][j] = (1.0f - z) * nval + z * hp;
      }
    }
    __asm__ volatile("s_waitcnt lgkmcnt(0)" ::: "memory");

    // u = hn@A, v = hn@B  (A=Wc1 rows 0..127, B=rows 128..255)
#pragma unroll
    for (int j2 = 0; j2 < 2; ++j2) {
      int j = lane + 64 * j2;
      float au[8], av[8];
#pragma unroll
      for (int m = 0; m < 8; ++m) { au[m] = 0.f; av[m] = 0.f; }
      for (int k4 = 0; k4 < HID / 4; ++k4) {
        float4 hv[8];
#pragma unroll
        for (int m = 0; m < 8; ++m)
          hv[m] = *reinterpret_cast<const float4*>(&hn_lds[w][m][k4 * 4]);
#pragma unroll
        for (int kk = 0; kk < 4; ++kk) {
          int k = k4 * 4 + kk;
          float wa = Wc1[k * HID + j];
          float wb = Wc1[(128 + k) * HID + j];
#pragma unroll
          for (int m = 0; m < 8; ++m) {
            float h = kk == 0 ? hv[m].x : kk == 1 ? hv[m].y : kk == 2 ? hv[m].z : hv[m].w;
            au[m] = fmaf(h, wa, au[m]);
            av[m] = fmaf(h, wb, av[m]);
          }
        }
      }
#pragma unroll
      for (int m = 0; m < 8; ++m) {
        u[(n0 + m) * HID + j] = au[m];
        vv[(n0 + m) * HID + j] = av[m];
      }
    }
  }
}

// ---------------- Kernel 3: per-edge classifier ----------------
__global__ __launch_bounds__(256) void cls_kernel(
    const float* __restrict__ u, const float* __restrict__ vv,
    const float* __restrict__ ea, const int* __restrict__ ei,
    const float* __restrict__ Wc1, const float* __restrict__ bc1,
    const float* __restrict__ Wc2, const float* __restrict__ bc2,
    float* __restrict__ out) {
  __shared__ float C_lds[EDIM * HID];  // 16 KB: Wc1 rows 256..287
  const int lane = threadIdx.x & 63;
  const int w = threadIdx.x >> 6;
  for (int i = threadIdx.x; i < EDIM * HID; i += 256) C_lds[i] = Wc1[256 * HID + i];
  __syncthreads();
  const float bc1_0 = bc1[lane], bc1_1 = bc1[lane + 64];
  const float w2_0 = Wc2[lane], w2_1 = Wc2[lane + 64];
  const float bcc = bc2[0];

  const int gwave = blockIdx.x * 4 + w;
  const int nwave = gridDim.x * 4;
  for (int e = gwave; e < NE; e += nwave) {
    int s = ei[e], d = ei[NE + e];
    float t0 = u[s * HID + lane] + vv[d * HID + lane] + bc1_0;
    float t1 = u[s * HID + lane + 64] + vv[d * HID + lane + 64] + bc1_1;
    const float* eap = &ea[e * EDIM];
#pragma unroll 8
    for (int k = 0; k < EDIM; ++k) {
      float evv = eap[k];
      t0 = fmaf(evv, C_lds[k * HID + lane], t0);
      t1 = fmaf(evv, C_lds[k * HID + lane + 64], t1);
    }
    float sacc = fmaxf(t0, 0.f) * w2_0 + fmaxf(t1, 0.f) * w2_1;
    sacc = wsum(sacc);
    if (lane == 0) out[e] = sacc + bcc;
  }
}

extern "C" void kernel_launch(void* const* d_in, const int* in_sizes, int n_in,
                              void* d_out, int out_size, void* d_ws, size_t ws_size,
                              hipStream_t stream) {
  (void)in_sizes; (void)n_in; (void)out_size; (void)ws_size;
  const int* ei = (const int*)d_in[1];
  const float* ea = (const float*)d_in[2];
  const float* h_prev = (const float*)d_in[3];
  const float* W1 = (const float*)d_in[4];
  const float* b1 = (const float*)d_in[5];
  const float* g1 = (const float*)d_in[6];
  const float* be1 = (const float*)d_in[7];
  const float* W2 = (const float*)d_in[8];
  const float* b2 = (const float*)d_in[9];
  const float* g2 = (const float*)d_in[10];
  const float* be2 = (const float*)d_in[11];
  const float* Wih = (const float*)d_in[12];
  const float* bih = (const float*)d_in[13];
  const float* Whh = (const float*)d_in[14];
  const float* bhh = (const float*)d_in[15];
  const float* Wc1 = (const float*)d_in[16];
  const float* bc1 = (const float*)d_in[17];
  const float* Wc2 = (const float*)d_in[18];
  const float* bc2 = (const float*)d_in[19];

  char* ws = (char*)d_ws;
  float* aggr = (float*)(ws);                 // 25,600,000 B
  float* cnt  = (float*)(ws + 25600000);      //    200,000 B
  float* WihT = (float*)(ws + 25800000);      //    196,608 B
  float* WhhT = (float*)(ws + 25996608);      //    196,608 B (< 26,214,400)
  float* u    = (float*)(ws + 26214400);      // 25,600,000 B
  float* vv   = (float*)(ws + 51814400);      // 25,600,000 B (end ~77.4 MB)

  hipMemsetAsync(aggr, 0, 25800000, stream);  // aggr + cnt

  hipLaunchKernelGGL(transpose_w, dim3(192), dim3(256), 0, stream,
                     Wih, Whh, WihT, WhhT);
  hipLaunchKernelGGL(enc_kernel, dim3(256), dim3(512), 0, stream,
                     ea, ei, W1, b1, g1, be1, W2, b2, g2, be2, aggr, cnt);
  hipLaunchKernelGGL(gru_kernel, dim3(1563), dim3(256), 0, stream,
                     aggr, cnt, h_prev, WihT, bih, WhhT, bhh, Wc1, u, vv);
  hipLaunchKernelGGL(cls_kernel, dim3(2048), dim3(256), 0, stream,
                     u, vv, ea, ei, Wc1, bc1, Wc2, bc2, (float*)d_out);
}

// Round 3
// 840.920 us; speedup vs baseline: 13.4808x; 13.4808x over previous
//
#include <hip/hip_runtime.h>
#include <math.h>

#define NN 50000
#define NE 500000
#define HID 128
#define EDIM 32

__device__ __forceinline__ float wsum(float v) {
#pragma unroll
  for (int m = 1; m < 64; m <<= 1) v += __shfl_xor(v, m, 64);
  return v;
}

// ---------------- Kernel 0: transpose GRU weights to [k][3H] ----------------
__global__ __launch_bounds__(256) void transpose_w(
    const float* __restrict__ Wih, const float* __restrict__ Whh,
    float* __restrict__ WihT, float* __restrict__ WhhT) {
  int idx = blockIdx.x * 256 + threadIdx.x;
  if (idx < 3 * HID * HID) {
    int j = idx / HID, k = idx - j * HID;  // source: row j (3H), col k (H)
    WihT[k * (3 * HID) + j] = Wih[idx];
    WhhT[k * (3 * HID) + j] = Whh[idx];
  }
}

// ---------------- Kernel 1: edge encoder + scatter-add (round-1 form) -------
// wave handles 8 edges; weights from global (L1/L2 cached, coalesced),
// activations broadcast from per-wave LDS. VGPR ~84, no spills.
__global__ __launch_bounds__(256) void enc_kernel(
    const float* __restrict__ ea, const int* __restrict__ ei,
    const float* __restrict__ W1, const float* __restrict__ b1,
    const float* __restrict__ g1, const float* __restrict__ be1,
    const float* __restrict__ W2, const float* __restrict__ b2,
    const float* __restrict__ g2, const float* __restrict__ be2,
    float* __restrict__ aggr, float* __restrict__ cnt) {
  __shared__ float ea_lds[4][8][EDIM];
  __shared__ float h1_lds[4][8][HID];
  const int lane = threadIdx.x & 63;
  const int w = threadIdx.x >> 6;
  const int j0 = lane, j1 = lane + 64;
  const float b1_0 = b1[j0], b1_1 = b1[j1];
  const float g1_0 = g1[j0], g1_1 = g1[j1];
  const float be1_0 = be1[j0], be1_1 = be1[j1];
  const float b2_0 = b2[j0], b2_1 = b2[j1];
  const float g2_0 = g2[j0], g2_1 = g2[j1];
  const float be2_0 = be2[j0], be2_1 = be2[j1];

  const int gwave = blockIdx.x * 4 + w;
  const int nwave = gridDim.x * 4;
  for (int base = gwave * 8; base < NE; base += nwave * 8) {
#pragma unroll
    for (int t = 0; t < 4; ++t) {
      int idx = t * 64 + lane;
      int m = idx >> 5, k = idx & 31;
      ea_lds[w][m][k] = ea[(base + m) * EDIM + k];
    }
    __asm__ volatile("s_waitcnt lgkmcnt(0)" ::: "memory");

    float a0[8], a1[8];
#pragma unroll
    for (int m = 0; m < 8; ++m) { a0[m] = b1_0; a1[m] = b1_1; }
#pragma unroll 4
    for (int k = 0; k < EDIM; ++k) {
      float w0 = W1[k * HID + j0];
      float w1 = W1[k * HID + j1];
#pragma unroll
      for (int m = 0; m < 8; ++m) {
        float e = ea_lds[w][m][k];
        a0[m] = fmaf(e, w0, a0[m]);
        a1[m] = fmaf(e, w1, a1[m]);
      }
    }
    // LN1 + relu -> LDS
#pragma unroll
    for (int m = 0; m < 8; ++m) {
      float s = wsum(a0[m] + a1[m]);
      float mu = s * (1.0f / HID);
      float d0 = a0[m] - mu, d1 = a1[m] - mu;
      float q = wsum(d0 * d0 + d1 * d1);
      float inv = rsqrtf(q * (1.0f / HID) + 1e-5f);
      h1_lds[w][m][j0] = fmaxf(d0 * inv * g1_0 + be1_0, 0.0f);
      h1_lds[w][m][j1] = fmaxf(d1 * inv * g1_1 + be1_1, 0.0f);
    }
    __asm__ volatile("s_waitcnt lgkmcnt(0)" ::: "memory");

    // layer 2
#pragma unroll
    for (int m = 0; m < 8; ++m) { a0[m] = b2_0; a1[m] = b2_1; }
#pragma unroll 4
    for (int k = 0; k < HID; ++k) {
      float w0 = W2[k * HID + j0];
      float w1 = W2[k * HID + j1];
#pragma unroll
      for (int m = 0; m < 8; ++m) {
        float h = h1_lds[w][m][k];
        a0[m] = fmaf(h, w0, a0[m]);
        a1[m] = fmaf(h, w1, a1[m]);
      }
    }
    // LN2 + relu + scatter
#pragma unroll
    for (int m = 0; m < 8; ++m) {
      float s = wsum(a0[m] + a1[m]);
      float mu = s * (1.0f / HID);
      float d0 = a0[m] - mu, d1 = a1[m] - mu;
      float q = wsum(d0 * d0 + d1 * d1);
      float inv = rsqrtf(q * (1.0f / HID) + 1e-5f);
      float e0 = fmaxf(d0 * inv * g2_0 + be2_0, 0.0f);
      float e1 = fmaxf(d1 * inv * g2_1 + be2_1, 0.0f);
      int srcn = ei[base + m];
      atomicAdd(&aggr[srcn * HID + j0], e0);
      atomicAdd(&aggr[srcn * HID + j1], e1);
      if (lane == 0) atomicAdd(&cnt[srcn], 1.0f);
    }
  }
}

// ---------------- Kernel 2: GRU + u/v precompute (fused gates, scalar) ------
__global__ __launch_bounds__(256) void gru_kernel(
    const float* __restrict__ aggr, const float* __restrict__ cnt,
    const float* __restrict__ h_prev,
    const float* __restrict__ WihT, const float* __restrict__ bih,
    const float* __restrict__ WhhT, const float* __restrict__ bhh,
    const float* __restrict__ Wc1,
    float* __restrict__ u, float* __restrict__ vv) {
  __shared__ float a_lds[4][8][HID];
  __shared__ float h_lds[4][8][HID];
  __shared__ float hn_lds[4][8][HID];
  const int lane = threadIdx.x & 63;
  const int w = threadIdx.x >> 6;
  const float br_0 = bih[lane] + bhh[lane];
  const float br_1 = bih[64 + lane] + bhh[64 + lane];
  const float bz_0 = bih[128 + lane] + bhh[128 + lane];
  const float bz_1 = bih[192 + lane] + bhh[192 + lane];
  const float bni_0 = bih[256 + lane], bni_1 = bih[320 + lane];
  const float bnh_0 = bhh[256 + lane], bnh_1 = bhh[320 + lane];

  const int gwave = blockIdx.x * 4 + w;
  const int nwave = gridDim.x * 4;
  const int ntask = NN / 8;  // 6250
  for (int task = gwave; task < ntask; task += nwave) {
    int n0 = task * 8;
#pragma unroll
    for (int t = 0; t < 16; ++t) {
      int idx = t * 64 + lane;
      int m = idx >> 7, k = idx & 127;
      int node = n0 + m;
      float ic = 1.0f / fmaxf(cnt[node], 1.0f);
      a_lds[w][m][k] = aggr[node * HID + k] * ic;
      h_lds[w][m][k] = h_prev[node * HID + k];
    }
    __asm__ volatile("s_waitcnt lgkmcnt(0)" ::: "memory");

#pragma unroll
    for (int j2 = 0; j2 < 2; ++j2) {
      const int j = lane + 64 * j2;
      float accr[8], accz[8], axn[8], ahn[8];
      const float br = j2 == 0 ? br_0 : br_1;
      const float bz = j2 == 0 ? bz_0 : bz_1;
      const float bni = j2 == 0 ? bni_0 : bni_1;
      const float bnh = j2 == 0 ? bnh_0 : bnh_1;
#pragma unroll
      for (int m = 0; m < 8; ++m) {
        accr[m] = br; accz[m] = bz; axn[m] = bni; ahn[m] = bnh;
      }
      const float* wiT = WihT + j;
      const float* whT = WhhT + j;
#pragma unroll 2
      for (int k = 0; k < HID; ++k) {
        float wir = wiT[k * 384];
        float wiz = wiT[k * 384 + 128];
        float win = wiT[k * 384 + 256];
        float whr = whT[k * 384];
        float whz = whT[k * 384 + 128];
        float whn = whT[k * 384 + 256];
#pragma unroll
        for (int m = 0; m < 8; ++m) {
          float a = a_lds[w][m][k], h = h_lds[w][m][k];
          accr[m] = fmaf(a, wir, accr[m]);
          accr[m] = fmaf(h, whr, accr[m]);
          accz[m] = fmaf(a, wiz, accz[m]);
          accz[m] = fmaf(h, whz, accz[m]);
          axn[m] = fmaf(a, win, axn[m]);
          ahn[m] = fmaf(h, whn, ahn[m]);
        }
      }
#pragma unroll
      for (int m = 0; m < 8; ++m) {
        float r = 1.0f / (1.0f + expf(-accr[m]));
        float z = 1.0f / (1.0f + expf(-accz[m]));
        float nval = tanhf(axn[m] + r * ahn[m]);
        float hp = h_lds[w][m][j];
        hn_lds[w][m][j] = (1.0f - z) * nval + z * hp;
      }
    }
    __asm__ volatile("s_waitcnt lgkmcnt(0)" ::: "memory");

    // u = hn@A, v = hn@B  (A=Wc1 rows 0..127, B=rows 128..255)
#pragma unroll
    for (int j2 = 0; j2 < 2; ++j2) {
      int j = lane + 64 * j2;
      float au[8], av[8];
#pragma unroll
      for (int m = 0; m < 8; ++m) { au[m] = 0.f; av[m] = 0.f; }
#pragma unroll 4
      for (int k = 0; k < HID; ++k) {
        float wa = Wc1[k * HID + j];
        float wb = Wc1[(128 + k) * HID + j];
#pragma unroll
        for (int m = 0; m < 8; ++m) {
          float h = hn_lds[w][m][k];
          au[m] = fmaf(h, wa, au[m]);
          av[m] = fmaf(h, wb, av[m]);
        }
      }
#pragma unroll
      for (int m = 0; m < 8; ++m) {
        u[(n0 + m) * HID + j] = au[m];
        vv[(n0 + m) * HID + j] = av[m];
      }
    }
  }
}

// ---------------- Kernel 3: per-edge classifier ----------------
__global__ __launch_bounds__(256) void cls_kernel(
    const float* __restrict__ u, const float* __restrict__ vv,
    const float* __restrict__ ea, const int* __restrict__ ei,
    const float* __restrict__ Wc1, const float* __restrict__ bc1,
    const float* __restrict__ Wc2, const float* __restrict__ bc2,
    float* __restrict__ out) {
  __shared__ float C_lds[EDIM * HID];  // 16 KB: Wc1 rows 256..287
  const int lane = threadIdx.x & 63;
  const int w = threadIdx.x >> 6;
  for (int i = threadIdx.x; i < EDIM * HID; i += 256) C_lds[i] = Wc1[256 * HID + i];
  __syncthreads();
  const float bc1_0 = bc1[lane], bc1_1 = bc1[lane + 64];
  const float w2_0 = Wc2[lane], w2_1 = Wc2[lane + 64];
  const float bcc = bc2[0];

  const int gwave = blockIdx.x * 4 + w;
  const int nwave = gridDim.x * 4;
  for (int e = gwave; e < NE; e += nwave) {
    int s = ei[e], d = ei[NE + e];
    float t0 = u[s * HID + lane] + vv[d * HID + lane] + bc1_0;
    float t1 = u[s * HID + lane + 64] + vv[d * HID + lane + 64] + bc1_1;
    const float* eap = &ea[e * EDIM];
#pragma unroll 8
    for (int k = 0; k < EDIM; ++k) {
      float evv = eap[k];
      t0 = fmaf(evv, C_lds[k * HID + lane], t0);
      t1 = fmaf(evv, C_lds[k * HID + lane + 64], t1);
    }
    float sacc = fmaxf(t0, 0.f) * w2_0 + fmaxf(t1, 0.f) * w2_1;
    sacc = wsum(sacc);
    if (lane == 0) out[e] = sacc + bcc;
  }
}

extern "C" void kernel_launch(void* const* d_in, const int* in_sizes, int n_in,
                              void* d_out, int out_size, void* d_ws, size_t ws_size,
                              hipStream_t stream) {
  (void)in_sizes; (void)n_in; (void)out_size; (void)ws_size;
  const int* ei = (const int*)d_in[1];
  const float* ea = (const float*)d_in[2];
  const float* h_prev = (const float*)d_in[3];
  const float* W1 = (const float*)d_in[4];
  const float* b1 = (const float*)d_in[5];
  const float* g1 = (const float*)d_in[6];
  const float* be1 = (const float*)d_in[7];
  const float* W2 = (const float*)d_in[8];
  const float* b2 = (const float*)d_in[9];
  const float* g2 = (const float*)d_in[10];
  const float* be2 = (const float*)d_in[11];
  const float* Wih = (const float*)d_in[12];
  const float* bih = (const float*)d_in[13];
  const float* Whh = (const float*)d_in[14];
  const float* bhh = (const float*)d_in[15];
  const float* Wc1 = (const float*)d_in[16];
  const float* bc1 = (const float*)d_in[17];
  const float* Wc2 = (const float*)d_in[18];
  const float* bc2 = (const float*)d_in[19];

  char* ws = (char*)d_ws;
  float* aggr = (float*)(ws);                 // 25,600,000 B
  float* cnt  = (float*)(ws + 25600000);      //    200,000 B
  float* WihT = (float*)(ws + 25800000);      //    196,608 B
  float* WhhT = (float*)(ws + 25996608);      //    196,608 B (< 26,214,400)
  float* u    = (float*)(ws + 26214400);      // 25,600,000 B
  float* vv   = (float*)(ws + 51814400);      // 25,600,000 B (end ~77.4 MB)

  hipMemsetAsync(aggr, 0, 25800000, stream);  // aggr + cnt

  hipLaunchKernelGGL(transpose_w, dim3(192), dim3(256), 0, stream,
                     Wih, Whh, WihT, WhhT);
  hipLaunchKernelGGL(enc_kernel, dim3(2048), dim3(256), 0, stream,
                     ea, ei, W1, b1, g1, be1, W2, b2, g2, be2, aggr, cnt);
  hipLaunchKernelGGL(gru_kernel, dim3(1563), dim3(256), 0, stream,
                     aggr, cnt, h_prev, WihT, bih, WhhT, bhh, Wc1, u, vv);
  hipLaunchKernelGGL(cls_kernel, dim3(2048), dim3(256), 0, stream,
                     u, vv, ea, ei, Wc1, bc1, Wc2, bc2, (float*)d_out);
}